// Round 11
// baseline (244.646 us; speedup 1.0000x reference)
//
#include <hip/hip_runtime.h>

#define BB 4
#define NN 4
#define TT 4
#define AA 128
#define DD 64
#define HWD 36864              // 192*192
#define NG (BB * TT * AA)      // 2048
#define CHUNKS 128
#define CPTS (HWD / CHUNKS)    // 288
#define NBLK (BB * TT * CHUNKS)  // 2048 blocks == 256 CU x 8 (co-resident)

__device__ __constant__ int c_ti[4] = {0, 0, 0, 1};
__device__ __constant__ int c_tj[4] = {1, 1, 2, 2};
__device__ __constant__ int c_tk[4] = {2, 3, 3, 3};

// Scalar-pipe (SMEM) view of read-only global data (wave-uniform addresses).
typedef const __attribute__((address_space(4))) float cfloat;

// Order-monotone float<->uint mapping: f1 < f2  <=>  fmap(f1) < fmap(f2).
__device__ __forceinline__ unsigned int fmap(float f) {
    const unsigned int b = __float_as_uint(f);
    return (b & 0x80000000u) ? ~b : (b | 0x80000000u);
}
__device__ __forceinline__ float funmap(unsigned int m) {
    const unsigned int b = (m & 0x80000000u) ? (m ^ 0x80000000u) : ~m;
    return __uint_as_float(b);
}

// ---------------------------------------------------------------------------
// Single fused kernel. Block=(bt,chunk), 128 threads = 128 queries of bt.
//  P1: scan1 chunk of image tj (query = anchor of ti), atomicMin into slot1.
//      Per-bt arrival counter + spin barrier (all 2048 blocks co-resident).
//  P2: idx_j from slot1; scan2 chunk of image tk; atomicMin into slot2.
//      Last-arriving block of each bt (unique old==126) becomes finisher:
//      reconstruct min_ij/min_jk/idx_k, dki vs in-reg anchors, feature SE,
//      block reduce, chained scalar final (proven R4-R10 tail).
// All cross-block state flows through device-scope atomics (no wide fences).
// Counters/slots armed to 0xFF.. by one memset node: ctr init 0xFFFFFFFF,
// after k increments value == k-1.
// ---------------------------------------------------------------------------
__global__ __launch_bounds__(128, 4) void
fused_kernel(const float* __restrict__ pts,
             const float* __restrict__ feats,
             const int* __restrict__ anchor_idx,
             unsigned long long* __restrict__ slot1,
             unsigned long long* __restrict__ slot2,
             unsigned int* __restrict__ ctr1,
             unsigned int* __restrict__ ctr2,
             unsigned int* __restrict__ ctr3,
             float* __restrict__ loss_bt,
             float* __restrict__ batch_ok,
             float* __restrict__ out) {
#pragma clang fp contract(off)
    const int tid = threadIdx.x;
    const int chunk = blockIdx.x & (CHUNKS - 1);
    const int bt = blockIdx.x >> 7;
    const int t = bt & 3;
    const int b = bt >> 2;
    const int g = bt * AA + tid;
    const int i_img = c_ti[t];
    const int j_img = c_tj[t];
    const int k_img = c_tk[t];

    // ---------------- Phase 1: scan1 ----------------
    const int ai = anchor_idx[g];
    const float* ap = pts + ((long)(b * NN + i_img) * HWD + ai) * 3;
    const float ax = ap[0], ay = ap[1], az = ap[2];
    {
        const float m2x = -2.0f * ax;
        const float m2y = -2.0f * ay;
        const float m2z = -2.0f * az;
        const float* sp =
            pts + ((long)(b * NN + j_img) * HWD + chunk * CPTS) * 3;
        cfloat* sps = (cfloat*)(unsigned long long)sp;   // scalar-pipe stream

        float best = 3.4e38f;
        int besti = 0;
#pragma unroll 8
        for (int p = 0; p < CPTS; ++p) {
            const float x = sps[3 * p + 0];
            const float y = sps[3 * p + 1];
            const float z = sps[3 * p + 2];
            const float s2 = x * x + y * y + z * z;
            const float key = fmaf(x, m2x, fmaf(y, m2y, fmaf(z, m2z, s2)));
            if (key < best) { best = key; besti = p; }  // asc -> first occ
        }
        const unsigned long long v =
            ((unsigned long long)fmap(best) << 32) |
            (unsigned int)(chunk * CPTS + besti);
        const unsigned long long o = atomicMin(&slot1[g], v);
        asm volatile("" ::"v"(o));   // consume: min completed before barrier
    }
    __syncthreads();

    // per-bt spin barrier (grid == co-resident capacity; s_sleep while wait)
    if (tid == 0) {
        const unsigned int o = atomicAdd(&ctr1[bt], 1u);
        asm volatile("" ::"v"(o));
        while (__hip_atomic_load(&ctr1[bt], __ATOMIC_RELAXED,
                                 __HIP_MEMORY_SCOPE_AGENT) != 127u)
            __builtin_amdgcn_s_sleep(8);
    }
    __syncthreads();

    // ---------------- Phase 2: scan2 ----------------
    const unsigned long long s1 = __hip_atomic_load(
        &slot1[g], __ATOMIC_RELAXED, __HIP_MEMORY_SCOPE_AGENT);
    const int ij = (int)(s1 & 0xFFFFFFFFull);
    const float* jp = pts + ((long)(b * NN + j_img) * HWD + ij) * 3;
    const float jx = jp[0], jy = jp[1], jz = jp[2];
    {
        const float m2x = -2.0f * jx;
        const float m2y = -2.0f * jy;
        const float m2z = -2.0f * jz;
        const float* sp =
            pts + ((long)(b * NN + k_img) * HWD + chunk * CPTS) * 3;
        cfloat* sps = (cfloat*)(unsigned long long)sp;

        float best = 3.4e38f;
        int besti = 0;
#pragma unroll 8
        for (int p = 0; p < CPTS; ++p) {
            const float x = sps[3 * p + 0];
            const float y = sps[3 * p + 1];
            const float z = sps[3 * p + 2];
            const float s2 = x * x + y * y + z * z;
            const float key = fmaf(x, m2x, fmaf(y, m2y, fmaf(z, m2z, s2)));
            if (key < best) { best = key; besti = p; }
        }
        const unsigned long long v =
            ((unsigned long long)fmap(best) << 32) |
            (unsigned int)(chunk * CPTS + besti);
        const unsigned long long o = atomicMin(&slot2[g], v);
        asm volatile("" ::"v"(o));
    }
    __syncthreads();

    __shared__ int s_last;
    if (tid == 0) s_last = (atomicAdd(&ctr2[bt], 1u) == 126u) ? 1 : 0;
    __syncthreads();
    if (!s_last) return;

    // ---------------- Finisher: one block per bt ----------------
    const float sq = ax * ax + ay * ay + az * az;
    const float min_ij = sqrtf(fmaxf(funmap((unsigned int)(s1 >> 32)) + sq, 0.0f));

    const float sqj = jx * jx + jy * jy + jz * jz;
    const unsigned long long s2v =
        atomicMin(&slot2[g], 0xFFFFFFFFFFFFFFFFull);   // coherent RMW read
    const float min_jk =
        sqrtf(fmaxf(funmap((unsigned int)(s2v >> 32)) + sqj, 0.0f));
    const int ik = (int)(s2v & 0xFFFFFFFFull);

    // dki: query = chosen k-point, scan 128 anchors staged in LDS
    __shared__ float aps[AA][3];
    aps[tid][0] = ax;
    aps[tid][1] = ay;
    aps[tid][2] = az;
    const float* kp = pts + ((long)(b * NN + k_img) * HWD + ik) * 3;
    const float kx = kp[0], ky = kp[1], kz = kp[2];
    const float sk = kx * kx + ky * ky + kz * kz;
    __syncthreads();

    float best = 3.4e38f;
    int besti = 0;
    for (int a2 = 0; a2 < AA; ++a2) {
        const float qx = aps[a2][0], qy = aps[a2][1], qz = aps[a2][2];
        const float s2 = qx * qx + qy * qy + qz * qz;
        const float dot = kx * qx + ky * qy + kz * qz;
        const float d2 = (sk + s2) - 2.0f * dot;
        if (d2 < best) { best = d2; besti = a2; }
    }
    const float min_ki = sqrtf(fmaxf(best, 0.0f));

    const int valid =
        (min_ij < 0.3f) && (min_jk < 0.3f) && (min_ki < 0.3f);

    // feat_ret: reference quirk — raw pixel index besti in [0,128)
    const float* fr = feats + ((long)(b * NN + i_img) * HWD + besti) * DD;
    const float* fa = feats + ((long)(b * NN + i_img) * HWD + ai) * DD;
    float snr = 0.0f, sna = 0.0f;
    for (int d = 0; d < DD; ++d) { const float x = fr[d]; snr += x * x; }
    for (int d = 0; d < DD; ++d) { const float y = fa[d]; sna += y * y; }
    const float nr = fmaxf(sqrtf(snr), 1e-12f);
    const float na = fmaxf(sqrtf(sna), 1e-12f);
    float se = 0.0f;
    for (int d = 0; d < DD; ++d) {
        const float x = fr[d] / nr - fa[d] / na;
        se += x * x;
    }

    __shared__ float sred[2][AA];
    sred[0][tid] = (float)valid;
    sred[1][tid] = valid ? se : 0.0f;
    __syncthreads();
    for (int s = 64; s > 0; s >>= 1) {
        if (tid < s) {
            sred[0][tid] += sred[0][tid + s];
            sred[1][tid] += sred[1][tid + s];
        }
        __syncthreads();
    }
    if (tid == 0) {
        const float cnt = sred[0][0];
        const float lbt = (cnt > 0.0f)
                              ? sred[1][0] / (fmaxf(cnt, 1.0f) * (float)DD)
                              : 0.0f;
        const float ok = (cnt >= 5.0f) ? 1.0f : 0.0f;
        atomicExch(&loss_bt[bt], lbt);     // device-scope write-through
        atomicExch(&batch_ok[bt], ok);
        __threadfence();                   // only 16 blocks — amortized
        const unsigned int old = atomicAdd(ctr3, 1u);
        if (old == 14u) {                  // 16th arrival (init 0xFFFFFFFF)
            float s = 0.0f;
            for (int tt = 0; tt < TT; ++tt) {
                float tc = 0.0f, sl = 0.0f;
                for (int bb = 0; bb < BB; ++bb) {
                    const float okv = atomicAdd(&batch_ok[bb * TT + tt], 0.0f);
                    const float lv = atomicAdd(&loss_bt[bb * TT + tt], 0.0f);
                    tc += okv;
                    sl += lv * okv;
                }
                s += (tc > 0.0f) ? sl / fmaxf(tc, 1.0f) : 0.0f;
            }
            out[0] = s / (float)TT;
        }
    }
}

extern "C" void kernel_launch(void* const* d_in, const int* in_sizes, int n_in,
                              void* d_out, int out_size, void* d_ws,
                              size_t ws_size, hipStream_t stream) {
    const float* feats = (const float*)d_in[0];   // (B,N,H,W,D) f32
    const float* pts = (const float*)d_in[1];     // (B,N,H,W,3) f32
    const int* anchor = (const int*)d_in[2];      // (B,T,A) i32
    float* out = (float*)d_out;

    unsigned long long* slot1 = (unsigned long long*)d_ws;   // NG u64
    unsigned long long* slot2 = slot1 + NG;                  // NG u64
    unsigned int* ctr1 = (unsigned int*)(slot2 + NG);        // 16 u32
    unsigned int* ctr2 = ctr1 + 16;                          // 16 u32
    unsigned int* ctr3 = ctr2 + 16;                          // 1  u32
    float* loss_bt = (float*)(ctr3 + 1);                     // 16 f32
    float* batch_ok = loss_bt + 16;                          // 16 f32

    // One memset arms slots (+inf sentinel) AND counters (0xFFFFFFFF).
    hipMemsetAsync(slot1, 0xFF,
                   2 * NG * sizeof(unsigned long long) + 33 * sizeof(unsigned int),
                   stream);

    fused_kernel<<<NBLK, 128, 0, stream>>>(pts, feats, anchor, slot1, slot2,
                                           ctr1, ctr2, ctr3, loss_bt,
                                           batch_ok, out);
}

// Round 12
// 107.504 us; speedup vs baseline: 2.2757x; 2.2757x over previous
//
#include <hip/hip_runtime.h>

#define BB 4
#define NN 4
#define TT 4
#define AA 128
#define DD 64
#define HWD 36864              // 192*192
#define NG (BB * TT * AA)      // 2048
#define CHUNKS 128
#define CPTS (HWD / CHUNKS)    // 288
#define NBLK (BB * TT * CHUNKS)  // 2048

__device__ __constant__ int c_ti[4] = {0, 0, 0, 1};
__device__ __constant__ int c_tj[4] = {1, 1, 2, 2};
__device__ __constant__ int c_tk[4] = {2, 3, 3, 3};

// Scalar-pipe (SMEM) view of read-only global data (wave-uniform addresses).
typedef const __attribute__((address_space(4))) float cfloat;

// Order-monotone float<->uint mapping: f1 < f2  <=>  fmap(f1) < fmap(f2).
__device__ __forceinline__ unsigned int fmap(float f) {
    const unsigned int b = __float_as_uint(f);
    return (b & 0x80000000u) ? ~b : (b | 0x80000000u);
}
__device__ __forceinline__ float funmap(unsigned int m) {
    const unsigned int b = (m & 0x80000000u) ? (m ^ 0x80000000u) : ~m;
    return __uint_as_float(b);
}

// ---------------------------------------------------------------------------
// K1: scan1 (R10 verbatim). Block=(bt,chunk), 128 threads = 128 anchor
// queries; streams raw pts of image tj via the scalar pipe; publishes the
// per-chunk argmin partial via u64 atomicMin:
//   val = (fmap(key) << 32) | global_point_idx
// -> min key, smaller-index tie-break == numpy first-occurrence argmin.
// Slots pre-armed to 0xFF.. (= +inf) by the memset node.
// ---------------------------------------------------------------------------
__global__ __launch_bounds__(128) void
scan1_kernel(const float* __restrict__ pts,
             const int* __restrict__ anchor_idx,
             unsigned long long* __restrict__ slot1) {
#pragma clang fp contract(off)
    const int chunk = blockIdx.x & (CHUNKS - 1);
    const int bt = blockIdx.x >> 7;
    const int t = bt & 3;
    const int b = bt >> 2;
    const int g = bt * AA + threadIdx.x;

    const int qpix = anchor_idx[g];
    const float* qp = pts + ((long)(b * NN + c_ti[t]) * HWD + qpix) * 3;
    const float m2x = -2.0f * qp[0];
    const float m2y = -2.0f * qp[1];
    const float m2z = -2.0f * qp[2];

    const float* sp =
        pts + ((long)(b * NN + c_tj[t]) * HWD + chunk * CPTS) * 3;
    cfloat* sps = (cfloat*)(unsigned long long)sp;   // scalar-pipe stream

    float best = 3.4e38f;
    int besti = 0;
#pragma unroll 8
    for (int p = 0; p < CPTS; ++p) {
        const float x = sps[3 * p + 0];
        const float y = sps[3 * p + 1];
        const float z = sps[3 * p + 2];
        const float s2 = x * x + y * y + z * z;
        const float key = fmaf(x, m2x, fmaf(y, m2y, fmaf(z, m2z, s2)));
        if (key < best) { best = key; besti = p; }   // ascending -> first occ
    }
    const unsigned long long v =
        ((unsigned long long)fmap(best) << 32) |
        (unsigned int)(chunk * CPTS + besti);
    atomicMin(&slot1[g], v);
}

// ---------------------------------------------------------------------------
// K2: scan2 + per-bt last-block finisher + chained scalar final (3-node plan).
// Wide path has NO fences: ordering rides on device-scope atomics — the
// atomicMin's returned old value is consumed before the arrival-increment,
// so the partial is at the coherence point before ctr2 says "arrived".
// Finisher (1 block per bt, the 128th arriver): reconstructs min_ij/min_jk/
// idx_k from the slots (idempotent atomicMin RMW = coherent read, R11-proven),
// dki vs LDS-staged anchors, feature SE, block reduce, counter-chained final.
// ---------------------------------------------------------------------------
__global__ __launch_bounds__(128) void
scan2_finish_kernel(const float* __restrict__ pts,
                    const float* __restrict__ feats,
                    const int* __restrict__ anchor_idx,
                    const unsigned long long* __restrict__ slot1,
                    unsigned long long* __restrict__ slot2,
                    unsigned int* __restrict__ ctr2,
                    unsigned int* __restrict__ ctr3,
                    float* __restrict__ loss_bt,
                    float* __restrict__ batch_ok,
                    float* __restrict__ out) {
#pragma clang fp contract(off)
    const int tid = threadIdx.x;
    const int chunk = blockIdx.x & (CHUNKS - 1);
    const int bt = blockIdx.x >> 7;
    const int t = bt & 3;
    const int b = bt >> 2;
    const int g = bt * AA + tid;
    const int i_img = c_ti[t];
    const int j_img = c_tj[t];
    const int k_img = c_tk[t];

    // idx_j from slot1 (previous kernel boundary = global sync)
    const unsigned long long s1 = slot1[g];
    const int ij = (int)(s1 & 0xFFFFFFFFull);
    const float* jp = pts + ((long)(b * NN + j_img) * HWD + ij) * 3;
    const float jx = jp[0], jy = jp[1], jz = jp[2];

    // scan2 (R10 body verbatim)
    {
        const float m2x = -2.0f * jx;
        const float m2y = -2.0f * jy;
        const float m2z = -2.0f * jz;
        const float* sp =
            pts + ((long)(b * NN + k_img) * HWD + chunk * CPTS) * 3;
        cfloat* sps = (cfloat*)(unsigned long long)sp;

        float best = 3.4e38f;
        int besti = 0;
#pragma unroll 8
        for (int p = 0; p < CPTS; ++p) {
            const float x = sps[3 * p + 0];
            const float y = sps[3 * p + 1];
            const float z = sps[3 * p + 2];
            const float s2 = x * x + y * y + z * z;
            const float key = fmaf(x, m2x, fmaf(y, m2y, fmaf(z, m2z, s2)));
            if (key < best) { best = key; besti = p; }
        }
        const unsigned long long v =
            ((unsigned long long)fmap(best) << 32) |
            (unsigned int)(chunk * CPTS + besti);
        const unsigned long long o = atomicMin(&slot2[g], v);
        asm volatile("" ::"v"(o));   // consume: min retired before arrival
    }
    __syncthreads();

    __shared__ int s_last;
    if (tid == 0)
        s_last = (atomicAdd(&ctr2[bt], 1u) == (unsigned)(CHUNKS - 2)) ? 1 : 0;
    __syncthreads();
    if (!s_last) return;

    // ---------------- finisher: one block per bt ----------------
    const int ai = anchor_idx[g];
    const float* ap = pts + ((long)(b * NN + i_img) * HWD + ai) * 3;
    const float ax = ap[0], ay = ap[1], az = ap[2];
    const float sq = ax * ax + ay * ay + az * az;
    const float min_ij =
        sqrtf(fmaxf(funmap((unsigned int)(s1 >> 32)) + sq, 0.0f));

    const float sqj = jx * jx + jy * jy + jz * jz;
    const unsigned long long s2v =
        atomicMin(&slot2[g], 0xFFFFFFFFFFFFFFFFull);   // coherent RMW read
    const float min_jk =
        sqrtf(fmaxf(funmap((unsigned int)(s2v >> 32)) + sqj, 0.0f));
    const int ik = (int)(s2v & 0xFFFFFFFFull);

    // dki: query = chosen k-point, scan 128 anchors staged in LDS
    __shared__ float aps[AA][3];
    aps[tid][0] = ax;
    aps[tid][1] = ay;
    aps[tid][2] = az;
    const float* kp = pts + ((long)(b * NN + k_img) * HWD + ik) * 3;
    const float kx = kp[0], ky = kp[1], kz = kp[2];
    const float sk = kx * kx + ky * ky + kz * kz;
    __syncthreads();

    float best = 3.4e38f;
    int besti = 0;
    for (int a2 = 0; a2 < AA; ++a2) {
        const float qx = aps[a2][0], qy = aps[a2][1], qz = aps[a2][2];
        const float s2 = qx * qx + qy * qy + qz * qz;
        const float dot = kx * qx + ky * qy + kz * qz;
        const float d2 = (sk + s2) - 2.0f * dot;
        if (d2 < best) { best = d2; besti = a2; }
    }
    const float min_ki = sqrtf(fmaxf(best, 0.0f));

    const int valid =
        (min_ij < 0.3f) && (min_jk < 0.3f) && (min_ki < 0.3f);

    // feat_ret: reference quirk — raw pixel index besti in [0,128)
    const float* fr = feats + ((long)(b * NN + i_img) * HWD + besti) * DD;
    const float* fa = feats + ((long)(b * NN + i_img) * HWD + ai) * DD;
    float snr = 0.0f, sna = 0.0f;
    for (int d = 0; d < DD; ++d) { const float x = fr[d]; snr += x * x; }
    for (int d = 0; d < DD; ++d) { const float y = fa[d]; sna += y * y; }
    const float nr = fmaxf(sqrtf(snr), 1e-12f);
    const float na = fmaxf(sqrtf(sna), 1e-12f);
    float se = 0.0f;
    for (int d = 0; d < DD; ++d) {
        const float x = fr[d] / nr - fa[d] / na;
        se += x * x;
    }

    __shared__ float sred[2][AA];
    sred[0][tid] = (float)valid;
    sred[1][tid] = valid ? se : 0.0f;
    __syncthreads();
    for (int s = 64; s > 0; s >>= 1) {
        if (tid < s) {
            sred[0][tid] += sred[0][tid + s];
            sred[1][tid] += sred[1][tid + s];
        }
        __syncthreads();
    }
    if (tid == 0) {
        const float cnt = sred[0][0];
        const float lbt = (cnt > 0.0f)
                              ? sred[1][0] / (fmaxf(cnt, 1.0f) * (float)DD)
                              : 0.0f;
        const float ok = (cnt >= 5.0f) ? 1.0f : 0.0f;
        atomicExch(&loss_bt[bt], lbt);     // device-scope write-through
        atomicExch(&batch_ok[bt], ok);
        __threadfence();                   // only 16 blocks — amortized
        const unsigned int old = atomicAdd(ctr3, 1u);
        if (old == 14u) {                  // 16th arrival (init 0xFFFFFFFF)
            float s = 0.0f;
            for (int tt = 0; tt < TT; ++tt) {
                float tc = 0.0f, sl = 0.0f;
                for (int bb = 0; bb < BB; ++bb) {
                    const float okv = atomicAdd(&batch_ok[bb * TT + tt], 0.0f);
                    const float lv = atomicAdd(&loss_bt[bb * TT + tt], 0.0f);
                    tc += okv;
                    sl += lv * okv;
                }
                s += (tc > 0.0f) ? sl / fmaxf(tc, 1.0f) : 0.0f;
            }
            out[0] = s / (float)TT;
        }
    }
}

extern "C" void kernel_launch(void* const* d_in, const int* in_sizes, int n_in,
                              void* d_out, int out_size, void* d_ws,
                              size_t ws_size, hipStream_t stream) {
    const float* feats = (const float*)d_in[0];   // (B,N,H,W,D) f32
    const float* pts = (const float*)d_in[1];     // (B,N,H,W,3) f32
    const int* anchor = (const int*)d_in[2];      // (B,T,A) i32
    float* out = (float*)d_out;

    unsigned long long* slot1 = (unsigned long long*)d_ws;   // NG u64
    unsigned long long* slot2 = slot1 + NG;                  // NG u64
    unsigned int* ctr2 = (unsigned int*)(slot2 + NG);        // 16 u32
    unsigned int* ctr3 = ctr2 + 16;                          // 1  u32
    float* loss_bt = (float*)(ctr3 + 1);                     // 16 f32
    float* batch_ok = loss_bt + 16;                          // 16 f32

    // One memset arms slots (+inf sentinel) AND counters (0xFFFFFFFF).
    hipMemsetAsync(slot1, 0xFF,
                   2 * NG * sizeof(unsigned long long) +
                       17 * sizeof(unsigned int),
                   stream);

    scan1_kernel<<<NBLK, 128, 0, stream>>>(pts, anchor, slot1);
    scan2_finish_kernel<<<NBLK, 128, 0, stream>>>(pts, feats, anchor, slot1,
                                                  slot2, ctr2, ctr3, loss_bt,
                                                  batch_ok, out);
}

// Round 13
// 68.989 us; speedup vs baseline: 3.5462x; 1.5583x over previous
//
#include <hip/hip_runtime.h>

#define BB 4
#define NN 4
#define TT 4
#define AA 128
#define DD 64
#define HWD 36864              // 192*192
#define NPTS (BB * NN * HWD)   // 589824
#define NG (BB * TT * AA)      // 2048
#define CHUNKS 128
#define CPTS (HWD / CHUNKS)    // 288
#define NBLK (BB * TT * CHUNKS)  // 2048

__device__ __constant__ int c_ti[4] = {0, 0, 0, 1};
__device__ __constant__ int c_tj[4] = {1, 1, 2, 2};
__device__ __constant__ int c_tk[4] = {2, 3, 3, 3};

// Scalar-pipe (SMEM) view of read-only global data (wave-uniform addresses).
typedef const __attribute__((address_space(4))) float cfloat;

// Order-monotone float<->uint mapping: f1 < f2  <=>  fmap(f1) < fmap(f2).
__device__ __forceinline__ unsigned int fmap(float f) {
    const unsigned int b = __float_as_uint(f);
    return (b & 0x80000000u) ? ~b : (b | 0x80000000u);
}
__device__ __forceinline__ float funmap(unsigned int m) {
    const unsigned int b = (m & 0x80000000u) ? (m ^ 0x80000000u) : ~m;
    return __uint_as_float(b);
}

// ---------------------------------------------------------------------------
// K0: prep — pack pts into float4 (x,y,z,|p|^2) AND arm slots/ctr.
// s2 expression identical (contract off) to the R10 inline version.
// Plain stores; the kernel boundary publishes them to the scan kernels
// (same guarantee the old memset node relied on). 2304 blocks x 256.
// ---------------------------------------------------------------------------
__global__ __launch_bounds__(256) void
prep_kernel(const float* __restrict__ pts, float4* __restrict__ pk4,
            unsigned long long* __restrict__ slots,   // slot1|slot2, 2*NG
            unsigned int* __restrict__ ctr) {
#pragma clang fp contract(off)
    const int idx = blockIdx.x * 256 + threadIdx.x;
    if (idx < NPTS) {
        const float x = pts[idx * 3 + 0];
        const float y = pts[idx * 3 + 1];
        const float z = pts[idx * 3 + 2];
        pk4[idx] = make_float4(x, y, z, x * x + y * y + z * z);
    }
    if (blockIdx.x == 0) {
        for (int s = threadIdx.x; s < 2 * NG; s += 256)
            slots[s] = 0xFFFFFFFFFFFFFFFFull;        // +inf sentinel
        if (threadIdx.x == 0) ctr[0] = 0xFFFFFFFFu;  // after k incs: k-1
    }
}

// ---------------------------------------------------------------------------
// K1: scan1 (R10 structure; packed stream). Block=(bt,chunk), 128 threads =
// 128 anchor queries; wave-uniform float4 stream on the scalar pipe.
// Key = s2 - 2*dot; partial published via u64 atomicMin:
//   val = (fmap(key) << 32) | global_point_idx
// -> min key, smaller-index tie-break == numpy first-occurrence argmin.
// ---------------------------------------------------------------------------
__global__ __launch_bounds__(128) void
scan1_kernel(const float4* __restrict__ pk4,
             const int* __restrict__ anchor_idx,
             unsigned long long* __restrict__ slot1) {
    const int chunk = blockIdx.x & (CHUNKS - 1);
    const int bt = blockIdx.x >> 7;
    const int t = bt & 3;
    const int b = bt >> 2;
    const int g = bt * AA + threadIdx.x;

    const int qpix = anchor_idx[g];
    const float4 q = pk4[(b * NN + c_ti[t]) * HWD + qpix];
    const float m2x = -2.0f * q.x;
    const float m2y = -2.0f * q.y;
    const float m2z = -2.0f * q.z;

    const float4* sp = pk4 + (b * NN + c_tj[t]) * HWD + chunk * CPTS;
    cfloat* sps = (cfloat*)(unsigned long long)sp;   // scalar-pipe stream

    float best = 3.4e38f;
    int besti = 0;
#pragma unroll 8
    for (int p = 0; p < CPTS; ++p) {
        const float x = sps[4 * p + 0];
        const float y = sps[4 * p + 1];
        const float z = sps[4 * p + 2];
        const float w = sps[4 * p + 3];
        const float key = fmaf(x, m2x, fmaf(y, m2y, fmaf(z, m2z, w)));
        if (key < best) { best = key; besti = p; }   // ascending -> first occ
    }
    const unsigned long long v =
        ((unsigned long long)fmap(best) << 32) |
        (unsigned int)(chunk * CPTS + besti);
    atomicMin(&slot1[g], v);   // non-returning: fire-and-forget
}

// ---------------------------------------------------------------------------
// K2: scan2 (R10 structure; packed stream). idx_j from slot1 low bits.
// ---------------------------------------------------------------------------
__global__ __launch_bounds__(128) void
scan2_kernel(const float4* __restrict__ pk4,
             const unsigned long long* __restrict__ slot1,
             unsigned long long* __restrict__ slot2) {
    const int tid = threadIdx.x;
    const int chunk = blockIdx.x & (CHUNKS - 1);
    const int bt = blockIdx.x >> 7;
    const int t = bt & 3;
    const int b = bt >> 2;
    const int g = bt * AA + tid;

    const int ij = (int)(slot1[g] & 0xFFFFFFFFull);
    const float4 jq = pk4[(b * NN + c_tj[t]) * HWD + ij];
    const float m2x = -2.0f * jq.x;
    const float m2y = -2.0f * jq.y;
    const float m2z = -2.0f * jq.z;

    const float4* sp = pk4 + (b * NN + c_tk[t]) * HWD + chunk * CPTS;
    cfloat* sps = (cfloat*)(unsigned long long)sp;

    float best = 3.4e38f;
    int besti = 0;
#pragma unroll 8
    for (int p = 0; p < CPTS; ++p) {
        const float x = sps[4 * p + 0];
        const float y = sps[4 * p + 1];
        const float z = sps[4 * p + 2];
        const float w = sps[4 * p + 3];
        const float key = fmaf(x, m2x, fmaf(y, m2y, fmaf(z, m2z, w)));
        if (key < best) { best = key; besti = p; }
    }
    const unsigned long long v =
        ((unsigned long long)fmap(best) << 32) |
        (unsigned int)(chunk * CPTS + besti);
    atomicMin(&slot2[g], v);
}

// ---------------------------------------------------------------------------
// K3: pass3 + chained final (16 blocks, 128 threads). R10 body; SE loops
// vectorized to float4 with EXACTLY preserved accumulation order (R6-proven);
// final tail's 32 atomic loads parallelized across 16 lanes (same values,
// same reduce order).
// ---------------------------------------------------------------------------
__global__ __launch_bounds__(128) void
pass3_kernel(const float* __restrict__ pts,
             const float* __restrict__ feats,
             const int* __restrict__ anchor_idx,
             const unsigned long long* __restrict__ slot1,
             const unsigned long long* __restrict__ slot2,
             float* __restrict__ loss_bt,
             float* __restrict__ batch_ok,
             unsigned int* __restrict__ ctr,
             float* __restrict__ out) {
#pragma clang fp contract(off)
    const int bt = blockIdx.x;
    const int t = bt & 3;
    const int b = bt >> 2;
    const int i = c_ti[t];
    const int k = c_tk[t];
    const int tid = threadIdx.x;
    const int g = bt * AA + tid;

    // anchor point & |q|^2 (raw pts, same expression as R10)
    const int ai = anchor_idx[g];
    const float* ap = pts + ((long)(b * NN + i) * HWD + ai) * 3;
    const float ax = ap[0], ay = ap[1], az = ap[2];
    const float sq = ax * ax + ay * ay + az * az;

    // min_ij from slot1
    const unsigned long long s1 = slot1[g];
    const float min_ij = sqrtf(fmaxf(funmap((unsigned int)(s1 >> 32)) + sq, 0.0f));
    const int ij = (int)(s1 & 0xFFFFFFFFull);

    // min_jk from slot2 (needs |pj|^2)
    const float* jp = pts + ((long)(b * NN + c_tj[t]) * HWD + ij) * 3;
    const float jx = jp[0], jy = jp[1], jz = jp[2];
    const float sqj = jx * jx + jy * jy + jz * jz;
    const unsigned long long s2v = slot2[g];
    const float min_jk =
        sqrtf(fmaxf(funmap((unsigned int)(s2v >> 32)) + sqj, 0.0f));
    const int ik = (int)(s2v & 0xFFFFFFFFull);

    // dki
    __shared__ float aps[AA][3];
    aps[tid][0] = ax;
    aps[tid][1] = ay;
    aps[tid][2] = az;
    const float* kp = pts + ((long)(b * NN + k) * HWD + ik) * 3;
    const float kx = kp[0], ky = kp[1], kz = kp[2];
    const float sk = kx * kx + ky * ky + kz * kz;
    __syncthreads();

    float best = 3.4e38f;
    int besti = 0;
    for (int a2 = 0; a2 < AA; ++a2) {
        const float qx = aps[a2][0], qy = aps[a2][1], qz = aps[a2][2];
        const float s2 = qx * qx + qy * qy + qz * qz;
        const float dot = kx * qx + ky * qy + kz * qz;
        const float d2 = (sk + s2) - 2.0f * dot;
        if (d2 < best) { best = d2; besti = a2; }
    }
    const float min_ki = sqrtf(fmaxf(best, 0.0f));

    const int valid =
        (min_ij < 0.3f) && (min_jk < 0.3f) && (min_ki < 0.3f);

    // feat_ret: reference quirk — raw pixel index besti in [0,128).
    // float4 loads; accumulation order identical to the scalar d-loop.
    const float4* fr4 =
        (const float4*)(feats + ((long)(b * NN + i) * HWD + besti) * DD);
    const float4* fa4 =
        (const float4*)(feats + ((long)(b * NN + i) * HWD + ai) * DD);
    float snr = 0.0f, sna = 0.0f;
#pragma unroll
    for (int r = 0; r < 16; ++r) {
        const float4 v = fr4[r];
        snr = snr + v.x * v.x; snr = snr + v.y * v.y;
        snr = snr + v.z * v.z; snr = snr + v.w * v.w;
    }
#pragma unroll
    for (int r = 0; r < 16; ++r) {
        const float4 v = fa4[r];
        sna = sna + v.x * v.x; sna = sna + v.y * v.y;
        sna = sna + v.z * v.z; sna = sna + v.w * v.w;
    }
    const float nr = fmaxf(sqrtf(snr), 1e-12f);
    const float na = fmaxf(sqrtf(sna), 1e-12f);
    float se = 0.0f;
#pragma unroll
    for (int r = 0; r < 16; ++r) {
        const float4 u = fr4[r];
        const float4 v = fa4[r];
        float x;
        x = u.x / nr - v.x / na; se = se + x * x;
        x = u.y / nr - v.y / na; se = se + x * x;
        x = u.z / nr - v.z / na; se = se + x * x;
        x = u.w / nr - v.w / na; se = se + x * x;
    }

    __shared__ float sred[2][AA];
    sred[0][tid] = (float)valid;
    sred[1][tid] = valid ? se : 0.0f;
    __syncthreads();
    for (int s = 64; s > 0; s >>= 1) {
        if (tid < s) {
            sred[0][tid] += sred[0][tid + s];
            sred[1][tid] += sred[1][tid + s];
        }
        __syncthreads();
    }

    __shared__ int s_fin;
    if (tid == 0) {
        const float cnt = sred[0][0];
        const float lbt = (cnt > 0.0f)
                              ? sred[1][0] / (fmaxf(cnt, 1.0f) * (float)DD)
                              : 0.0f;
        const float ok = (cnt >= 5.0f) ? 1.0f : 0.0f;
        atomicExch(&loss_bt[bt], lbt);     // device-scope write-through
        atomicExch(&batch_ok[bt], ok);
        __threadfence();                   // only 16 blocks — amortized
        s_fin = (atomicAdd(ctr, 1u) == 14u) ? 1 : 0;   // 16th arrival
    }
    __syncthreads();
    if (!s_fin) return;

    // last block: gather the 16 (loss, ok) pairs in parallel, reduce in the
    // exact reference order.
    __shared__ float sok[16], slo[16];
    if (tid < 16) {
        sok[tid] = atomicAdd(&batch_ok[tid], 0.0f);   // coherent loads
        slo[tid] = atomicAdd(&loss_bt[tid], 0.0f);
    }
    __syncthreads();
    if (tid == 0) {
        float s = 0.0f;
        for (int tt = 0; tt < TT; ++tt) {
            float tc = 0.0f, sl = 0.0f;
            for (int bb = 0; bb < BB; ++bb) {
                const float okv = sok[bb * TT + tt];
                tc += okv;
                sl += slo[bb * TT + tt] * okv;
            }
            s += (tc > 0.0f) ? sl / fmaxf(tc, 1.0f) : 0.0f;
        }
        out[0] = s / (float)TT;
    }
}

extern "C" void kernel_launch(void* const* d_in, const int* in_sizes, int n_in,
                              void* d_out, int out_size, void* d_ws,
                              size_t ws_size, hipStream_t stream) {
    const float* feats = (const float*)d_in[0];   // (B,N,H,W,D) f32
    const float* pts = (const float*)d_in[1];     // (B,N,H,W,3) f32
    const int* anchor = (const int*)d_in[2];      // (B,T,A) i32
    float* out = (float*)d_out;

    float* ws = (float*)d_ws;
    float4* pk4 = (float4*)ws;                               // 9.4 MB
    unsigned long long* slot1 = (unsigned long long*)(ws + NPTS * 4);
    unsigned long long* slot2 = slot1 + NG;
    unsigned int* ctr = (unsigned int*)(slot2 + NG);         // 1 u32
    float* loss_bt = (float*)(ctr + 1);                      // 16 f32
    float* batch_ok = loss_bt + 16;                          // 16 f32

    prep_kernel<<<(NPTS + 255) / 256, 256, 0, stream>>>(pts, pk4, slot1, ctr);
    scan1_kernel<<<NBLK, 128, 0, stream>>>(pk4, anchor, slot1);
    scan2_kernel<<<NBLK, 128, 0, stream>>>(pk4, slot1, slot2);
    pass3_kernel<<<BB * TT, 128, 0, stream>>>(pts, feats, anchor, slot1,
                                              slot2, loss_bt, batch_ok, ctr,
                                              out);
}